// Round 1
// baseline (194.797 us; speedup 1.0000x reference)
//
#include <hip/hip_runtime.h>

// Chamfer loss: x,y (16, 4096, 3) fp32 -> scalar.
// One block per (batch, 128 x-points). Full y-batch staged in LDS (48 KB),
// broadcast-read as float4. Direct squared-difference per pair (7 VALU ops),
// per-thread running min, block-reduce sum, one atomicAdd per block.

constexpr int NPTS  = 4096;
constexpr int BLOCK = 128;   // 2 waves; grid = 16 * (4096/128) = 512 blocks

__global__ __launch_bounds__(BLOCK) void chamfer_kernel(
    const float* __restrict__ x, const float* __restrict__ y,
    float* __restrict__ out)
{
    __shared__ float sy[NPTS * 3];          // 48 KB: this batch's y points
    __shared__ float swsum[BLOCK / 64];

    const int chunks_per_batch = NPTS / BLOCK;          // 32
    const int b     = blockIdx.x / chunks_per_batch;
    const int chunk = blockIdx.x % chunks_per_batch;

    // Stage y[b] into LDS with float4 loads (16B coalesced).
    const float4* yb4 = (const float4*)(y + (size_t)b * NPTS * 3);
    float4* sy4 = (float4*)sy;
    for (int i = threadIdx.x; i < NPTS * 3 / 4; i += BLOCK) sy4[i] = yb4[i];

    // This thread's x point.
    const int n = chunk * BLOCK + threadIdx.x;
    const float* xp = x + ((size_t)b * NPTS + n) * 3;
    const float x0 = xp[0], x1 = xp[1], x2 = xp[2];

    __syncthreads();

    float m = 3.4e38f;
    #pragma unroll 2
    for (int j = 0; j < NPTS / 4; ++j) {
        // 4 points = 12 floats = 3 x ds_read_b128 (wave-uniform address -> broadcast)
        const float4 p = sy4[3 * j + 0];
        const float4 q = sy4[3 * j + 1];
        const float4 r = sy4[3 * j + 2];
        float t, d0, d1, d2, d3;
        t = x0 - p.x; d0 = t * t;
        t = x1 - p.y; d0 = fmaf(t, t, d0);
        t = x2 - p.z; d0 = fmaf(t, t, d0);

        t = x0 - p.w; d1 = t * t;
        t = x1 - q.x; d1 = fmaf(t, t, d1);
        t = x2 - q.y; d1 = fmaf(t, t, d1);

        t = x0 - q.z; d2 = t * t;
        t = x1 - q.w; d2 = fmaf(t, t, d2);
        t = x2 - r.x; d2 = fmaf(t, t, d2);

        t = x0 - r.y; d3 = t * t;
        t = x1 - r.z; d3 = fmaf(t, t, d3);
        t = x2 - r.w; d3 = fmaf(t, t, d3);

        m = fminf(m, fminf(fminf(d0, d1), fminf(d2, d3)));
    }

    // Sum of per-thread mins: wave shuffle reduce (width 64), then cross-wave.
    for (int off = 32; off > 0; off >>= 1)
        m += __shfl_down(m, off, 64);
    const int wave = threadIdx.x >> 6;
    if ((threadIdx.x & 63) == 0) swsum[wave] = m;
    __syncthreads();
    if (threadIdx.x == 0) {
        float s = 0.f;
        #pragma unroll
        for (int w = 0; w < BLOCK / 64; ++w) s += swsum[w];
        atomicAdd(out, s * (1.0f / NPTS));
    }
}

extern "C" void kernel_launch(void* const* d_in, const int* in_sizes, int n_in,
                              void* d_out, int out_size, void* d_ws, size_t ws_size,
                              hipStream_t stream) {
    const float* x = (const float*)d_in[0];
    const float* y = (const float*)d_in[1];
    float* out = (float*)d_out;

    // d_out is re-poisoned to 0xAA before every timed launch -> zero it.
    hipMemsetAsync(out, 0, sizeof(float), stream);

    const int nbatch = in_sizes[0] / (NPTS * 3);        // 16
    const int grid = nbatch * (NPTS / BLOCK);           // 512
    chamfer_kernel<<<grid, BLOCK, 0, stream>>>(x, y, out);
}

// Round 2
// 93.384 us; speedup vs baseline: 2.0860x; 2.0860x over previous
//
#include <hip/hip_runtime.h>

// Chamfer loss: x,y (16, 4096, 3) fp32 -> scalar.
// Pass 1: grid = 16 batches x 4 x-chunks(1024) x 8 y-chunks(512) = 512 blocks,
//   256 threads, 4 x-points/thread in registers, 512 y-points staged in 6 KB LDS.
//   Partial min per x-point combined across y-chunk blocks with atomicMin on
//   uint bits (squared dists >= 0, so float order == uint order).
// Pass 2: sum the 16*4096 mins, scale by 1/4096, atomicAdd into out.

constexpr int NPTS    = 4096;
constexpr int NBATCH  = 16;
constexpr int BLOCK   = 256;
constexpr int XPT     = 4;                   // x-points per thread
constexpr int XCHUNK  = BLOCK * XPT;         // 1024 x-points per block
constexpr int YTILE   = 512;                 // y-points per block (6 KB LDS)
constexpr int NXC     = NPTS / XCHUNK;       // 4
constexpr int NYC     = NPTS / YTILE;        // 8

__global__ __launch_bounds__(BLOCK) void chamfer_min_kernel(
    const float* __restrict__ x, const float* __restrict__ y,
    unsigned int* __restrict__ ws_min)
{
    __shared__ float4 sy4[YTILE * 3 / 4];    // 384 float4 = 6 KB

    const int b      = blockIdx.x >> 5;          // / (NXC*NYC)
    const int xchunk = (blockIdx.x >> 3) & (NXC - 1);
    const int ychunk = blockIdx.x & (NYC - 1);

    // Stage this block's y tile (512 points) into LDS.
    const float4* yb4 = (const float4*)(y + ((size_t)b * NPTS + ychunk * YTILE) * 3);
    for (int i = threadIdx.x; i < YTILE * 3 / 4; i += BLOCK) sy4[i] = yb4[i];

    // Load this thread's 4 consecutive x-points (12 floats = 3 float4).
    const int xbase = xchunk * XCHUNK + threadIdx.x * XPT;
    const float4* xp4 = (const float4*)(x + ((size_t)b * NPTS + xbase) * 3);
    const float4 a0 = xp4[0], a1 = xp4[1], a2 = xp4[2];
    const float xa[XPT][3] = {
        {a0.x, a0.y, a0.z}, {a0.w, a1.x, a1.y},
        {a1.z, a1.w, a2.x}, {a2.y, a2.z, a2.w}};

    __syncthreads();

    float m[XPT];
    #pragma unroll
    for (int i = 0; i < XPT; ++i) m[i] = 3.4e38f;

    #pragma unroll 2
    for (int j = 0; j < YTILE / 4; ++j) {
        const float4 p = sy4[3 * j + 0];
        const float4 q = sy4[3 * j + 1];
        const float4 r = sy4[3 * j + 2];
        const float ya[4][3] = {
            {p.x, p.y, p.z}, {p.w, q.x, q.y},
            {q.z, q.w, r.x}, {r.y, r.z, r.w}};
        #pragma unroll
        for (int k = 0; k < 4; ++k) {
            #pragma unroll
            for (int i = 0; i < XPT; ++i) {
                const float d0 = xa[i][0] - ya[k][0];
                const float d1 = xa[i][1] - ya[k][1];
                const float d2 = xa[i][2] - ya[k][2];
                const float d  = fmaf(d2, d2, fmaf(d1, d1, d0 * d0));
                m[i] = fminf(m[i], d);
            }
        }
    }

    // Combine across y-chunk blocks: uint atomicMin (ws pre-set to 0xFFFFFFFF).
    unsigned int* wm = ws_min + (size_t)b * NPTS + xbase;
    #pragma unroll
    for (int i = 0; i < XPT; ++i)
        atomicMin(&wm[i], __float_as_uint(m[i]));
}

__global__ __launch_bounds__(BLOCK) void chamfer_sum_kernel(
    const unsigned int* __restrict__ ws_min, float* __restrict__ out)
{
    __shared__ float swsum[BLOCK / 64];
    const int total = NBATCH * NPTS;
    float s = 0.f;
    for (int i = blockIdx.x * BLOCK + threadIdx.x; i < total;
         i += gridDim.x * BLOCK)
        s += __uint_as_float(ws_min[i]);

    for (int off = 32; off > 0; off >>= 1)
        s += __shfl_down(s, off, 64);
    const int wave = threadIdx.x >> 6;
    if ((threadIdx.x & 63) == 0) swsum[wave] = s;
    __syncthreads();
    if (threadIdx.x == 0) {
        float t = 0.f;
        #pragma unroll
        for (int w = 0; w < BLOCK / 64; ++w) t += swsum[w];
        atomicAdd(out, t * (1.0f / NPTS));
    }
}

extern "C" void kernel_launch(void* const* d_in, const int* in_sizes, int n_in,
                              void* d_out, int out_size, void* d_ws, size_t ws_size,
                              hipStream_t stream) {
    const float* x = (const float*)d_in[0];
    const float* y = (const float*)d_in[1];
    float* out = (float*)d_out;
    unsigned int* ws_min = (unsigned int*)d_ws;

    // ws: 16*4096 uints -> 0xFFFFFFFF (= +inf for uint-min of nonneg floats).
    hipMemsetAsync(ws_min, 0xFF, (size_t)NBATCH * NPTS * sizeof(unsigned int), stream);
    hipMemsetAsync(out, 0, sizeof(float), stream);

    const int grid1 = NBATCH * NXC * NYC;    // 512
    chamfer_min_kernel<<<grid1, BLOCK, 0, stream>>>(x, y, ws_min);
    chamfer_sum_kernel<<<64, BLOCK, 0, stream>>>(ws_min, out);
}